// Round 10
// baseline (499.367 us; speedup 1.0000x reference)
//
#include <hip/hip_runtime.h>
#include <hip/hip_bf16.h>

#define N_NODES 50000
#define N_EDGES 800000
// HEADS=4, OUT_CH=64, F=256 hard-coded. All harness I/O float32.
// Internal H layout INTERLEAVED: H[node*256 + c*4 + h]  (c=channel 0..63, h=head 0..3)

typedef __attribute__((ext_vector_type(8))) short short8;   // 8 bf16 = 4 VGPRs (MFMA A/B frag)
typedef __attribute__((ext_vector_type(4))) float floatx4;  // MFMA C/D frag
typedef __attribute__((ext_vector_type(2))) uint uintx2;

__device__ __forceinline__ ushort f2bf(float f) {           // RNE f32->bf16 bits
    uint u = __float_as_uint(f);
    uint r = u + 0x7FFFu + ((u >> 16) & 1u);
    return (ushort)(r >> 16);
}
__device__ __forceinline__ float bfu2f(ushort h) {
    return __uint_as_float(((uint)h) << 16);
}
__device__ __forceinline__ float bflo(uint u) { return __uint_as_float(u << 16); }
__device__ __forceinline__ float bfhi(uint u) { return __uint_as_float(u & 0xffff0000u); }
__device__ __forceinline__ float lrelu(float e) { return e >= 0.f ? e : 0.2f * e; }

// ---------------- CSR build (dst-sorted incoming edge lists) ----------------
__global__ void deg_kernel(const int* __restrict__ dst, int* __restrict__ cnt, int E) {
    int i = blockIdx.x * blockDim.x + threadIdx.x;
    if (i < E) atomicAdd(&cnt[dst[i]], 1);
}

__global__ __launch_bounds__(256) void scan1_kernel(const int* __restrict__ cnt,
                                                    int* __restrict__ excl,
                                                    int* __restrict__ partial, int n) {
    __shared__ int sd[256];
    int tid = threadIdx.x;
    int i = blockIdx.x * 256 + tid;
    int v = (i < n) ? cnt[i] : 0;
    sd[tid] = v;
    __syncthreads();
    #pragma unroll
    for (int off = 1; off < 256; off <<= 1) {
        int t = (tid >= off) ? sd[tid - off] : 0;
        __syncthreads();
        sd[tid] += t;
        __syncthreads();
    }
    if (i < n) excl[i] = sd[tid] - v;
    if (tid == 255) partial[blockIdx.x] = sd[255];
}

__global__ __launch_bounds__(256) void scan2_kernel(int* __restrict__ partial, int nb) {
    __shared__ int sd[256];
    int tid = threadIdx.x;
    int v = (tid < nb) ? partial[tid] : 0;
    sd[tid] = v;
    __syncthreads();
    #pragma unroll
    for (int off = 1; off < 256; off <<= 1) {
        int t = (tid >= off) ? sd[tid - off] : 0;
        __syncthreads();
        sd[tid] += t;
        __syncthreads();
    }
    if (tid < nb) partial[tid] = sd[tid] - v;   // exclusive
}

__global__ __launch_bounds__(256) void scan3_kernel(const int* __restrict__ excl,
                                                    const int* __restrict__ partial,
                                                    int* __restrict__ row_ptr,
                                                    int* __restrict__ row_tmp, int n) {
    int i = blockIdx.x * 256 + threadIdx.x;
    if (i < n) {
        int v = excl[i] + partial[blockIdx.x];
        row_ptr[i] = v;
        row_tmp[i] = v;
    }
    if (i == 0) row_ptr[n] = N_EDGES;
}

__global__ void scatter_kernel(const int* __restrict__ src, const int* __restrict__ dst,
                               int* __restrict__ row_tmp, int* __restrict__ sorted_src,
                               int* __restrict__ sorted_dst, int E) {
    int i = blockIdx.x * blockDim.x + threadIdx.x;
    if (i < E) {
        int d = dst[i];
        int p = atomicAdd(&row_tmp[d], 1);
        sorted_src[p] = src[i];
        sorted_dst[p] = d;
    }
}

// ------ W prep: transpose + bf16 hi/lo split (+ unused fused att rows) ------
__global__ __launch_bounds__(320) void prep_w(const float* __restrict__ W1,
                                              const float* __restrict__ W2,
                                              const float* __restrict__ as1,
                                              const float* __restrict__ ad1,
                                              const float* __restrict__ as2,
                                              const float* __restrict__ ad2,
                                              ushort* __restrict__ Wt1_hi,
                                              ushort* __restrict__ Wt1_lo,
                                              ushort* __restrict__ Wt2_hi,
                                              ushort* __restrict__ Wt2_lo) {
    int t = threadIdx.x, k = blockIdx.x & 255;
    int l1 = (blockIdx.x < 256);
    const float* W = l1 ? W1 : W2;
    const float* as_ = l1 ? as1 : as2;
    const float* ad_ = l1 ? ad1 : ad2;
    ushort* Wh = l1 ? Wt1_hi : Wt2_hi;
    ushort* Wl = l1 ? Wt1_lo : Wt2_lo;
    if (t < 256) {
        float v = W[k * 256 + t];
        ushort hb = f2bf(v);
        Wh[t * 256 + k] = hb;
        Wl[t * 256 + k] = f2bf(v - bfu2f(hb));
    } else if (t < 264) {
        int j = t - 256;
        int h = j & 3;
        const float* vec = (j < 4) ? as_ : ad_;
        float acc = 0.f;
        for (int c = 0; c < 64; c++) acc += W[k * 256 + h * 64 + c] * vec[h * 64 + c];
        ushort hb = f2bf(acc);
        Wh[t * 256 + k] = hb;
        Wl[t * 256 + k] = f2bf(acc - bfu2f(hb));
    } else if (t < 272) {
        Wh[t * 256 + k] = 0;
        Wl[t * 256 + k] = 0;
    }
}

// ------- GEMM + fused attention logits, col-split, DBUF + RAW BARRIERS ------
// (R8-proven: one raw s_barrier + lgkmcnt(0) per k-step, W/A prefetch across
// barriers; do NOT replace the raw barrier with __syncthreads -- hipcc adds a
// vmcnt(0) drain there that kills cross-barrier load pipelining.)
__global__ __launch_bounds__(256) void gemm_att_kernel(const float* __restrict__ A,
                                                       const ushort* __restrict__ Wt_hi,
                                                       const ushort* __restrict__ Wt_lo,
                                                       const float* __restrict__ att_s,
                                                       const float* __restrict__ att_d,
                                                       ushort* __restrict__ H,
                                                       float* __restrict__ a_src,
                                                       float* __restrict__ a_dst, int M) {
    const int ROWP = 40;
    __shared__ ushort hi_s[2][128 * ROWP];   // 2 x 10 KB
    __shared__ ushort lo_s[2][128 * ROWP];   // 2 x 10 KB
    const int tid = threadIdx.x;
    const int wave = tid >> 6, lane = tid & 63;
    const int quad = lane >> 4, l16 = lane & 15;
    const int brow = blockIdx.x * 64;
    const int coff = blockIdx.y * 128;    // column offset (also Wt row offset)
    const int mrow = brow + wave * 16 + l16;
    const int mload = (mrow < M) ? mrow : (M - 1);

    floatx4 acc[8];
    #pragma unroll
    for (int t = 0; t < 8; t++) acc[t] = (floatx4){0.f, 0.f, 0.f, 0.f};

    // staging role: threads 0-127 stage hi, 128-255 stage lo; col = tid&127
    const int scol = tid & 127;
    const ushort* gW = ((tid < 128) ? Wt_hi : Wt_lo) + (size_t)(coff + scol) * 256;
    ushort* sB0 = ((tid < 128) ? &hi_s[0][0] : &lo_s[0][0]) + scol * ROWP;
    ushort* sB1 = ((tid < 128) ? &hi_s[1][0] : &lo_s[1][0]) + scol * ROWP;

    const float* ap = A + (size_t)mload * 256 + quad * 8;

    // prologue: W(0) -> regs -> buf0; A(0), A(1) -> regs
    short8 wreg[4];
    #pragma unroll
    for (int i = 0; i < 4; i++)
        wreg[i] = *reinterpret_cast<const short8*>(gW + i * 8);
    float4 af0[2], af1[2];
    af0[0] = *reinterpret_cast<const float4*>(ap);
    af1[0] = *reinterpret_cast<const float4*>(ap + 4);
    af0[1] = *reinterpret_cast<const float4*>(ap + 32);
    af1[1] = *reinterpret_cast<const float4*>(ap + 36);
    #pragma unroll
    for (int i = 0; i < 4; i++)
        *reinterpret_cast<short8*>(sB0 + i * 8) = wreg[i];
    asm volatile("s_waitcnt lgkmcnt(0)" ::: "memory");
    __builtin_amdgcn_s_barrier();

    #pragma unroll
    for (int t = 0; t < 8; t++) {
        const int cur = t & 1;
        if (t < 7) {                      // issue W(t+1): lands during this step
            #pragma unroll
            for (int i = 0; i < 4; i++)
                wreg[i] = *reinterpret_cast<const short8*>(gW + (t + 1) * 32 + i * 8);
        }
        // convert A(t) -> bf16 hi/lo
        float av[8] = {af0[cur].x, af0[cur].y, af0[cur].z, af0[cur].w,
                       af1[cur].x, af1[cur].y, af1[cur].z, af1[cur].w};
        short8 a_hi, a_lo;
        #pragma unroll
        for (int j = 0; j < 8; j++) {
            ushort hb = f2bf(av[j]);
            a_hi[j] = (short)hb;
            a_lo[j] = (short)f2bf(av[j] - bfu2f(hb));
        }
        if (t < 6) {                      // A(t+2): 2-deep, crosses one raw barrier
            af0[cur] = *reinterpret_cast<const float4*>(ap + (t + 2) * 32);
            af1[cur] = *reinterpret_cast<const float4*>(ap + (t + 2) * 32 + 4);
        }
        const ushort* rh = (cur == 0) ? &hi_s[0][0] : &hi_s[1][0];
        const ushort* rl = (cur == 0) ? &lo_s[0][0] : &lo_s[1][0];
        #pragma unroll
        for (int tt = 0; tt < 8; tt++) {
            int roff = (tt * 16 + l16) * ROWP + quad * 8;
            short8 b_hi = *reinterpret_cast<const short8*>(rh + roff);
            short8 b_lo = *reinterpret_cast<const short8*>(rl + roff);
            acc[tt] = __builtin_amdgcn_mfma_f32_16x16x32_bf16(a_hi, b_hi, acc[tt], 0, 0, 0);
            acc[tt] = __builtin_amdgcn_mfma_f32_16x16x32_bf16(a_hi, b_lo, acc[tt], 0, 0, 0);
            acc[tt] = __builtin_amdgcn_mfma_f32_16x16x32_bf16(a_lo, b_hi, acc[tt], 0, 0, 0);
        }
        if (t < 7) {                      // stage W(t+1) into the other buffer
            ushort* sBn = cur ? sB0 : sB1;
            #pragma unroll
            for (int i = 0; i < 4; i++)
                *reinterpret_cast<short8*>(sBn + i * 8) = wreg[i];
        }
        asm volatile("s_waitcnt lgkmcnt(0)" ::: "memory");
        __builtin_amdgcn_s_barrier();
    }
    // fused attention-logit partials: tiles 0-3 -> head coff/64, 4-7 -> +1
    const int hb = blockIdx.y * 2;
    float ps[2][4] = {}, pd[2][4] = {};
    #pragma unroll
    for (int t = 0; t < 8; t++) {
        int hh = t >> 2;
        float as_v = att_s[coff + t * 16 + l16];
        float ad_v = att_d[coff + t * 16 + l16];
        #pragma unroll
        for (int r = 0; r < 4; r++) {
            ps[hh][r] += acc[t][r] * as_v;
            pd[hh][r] += acc[t][r] * ad_v;
        }
    }
    #pragma unroll
    for (int off = 1; off < 16; off <<= 1) {
        #pragma unroll
        for (int hh = 0; hh < 2; hh++)
            #pragma unroll
            for (int r = 0; r < 4; r++) {
                ps[hh][r] += __shfl_xor(ps[hh][r], off, 64);
                pd[hh][r] += __shfl_xor(pd[hh][r], off, 64);
            }
    }
    if (l16 == 0) {
        #pragma unroll
        for (int r = 0; r < 4; r++) {
            int m = brow + wave * 16 + quad * 4 + r;
            if (m < M) {
                #pragma unroll
                for (int hh = 0; hh < 2; hh++) {
                    a_src[m * 4 + hb + hh] = ps[hh][r];
                    a_dst[m * 4 + hb + hh] = pd[hh][r];
                }
            }
        }
    }
    // store bf16 H, interleaved (c*4 + h), packed head-pairs: tiles t and t+4
    // share c = t*16 + l16 and hold heads hb, hb+1 -> one uint store.
    #pragma unroll
    for (int t = 0; t < 4; t++) {
        int c = t * 16 + l16;
        #pragma unroll
        for (int r = 0; r < 4; r++) {
            int m = brow + wave * 16 + quad * 4 + r;
            if (m < M) {
                uint pk = (uint)f2bf(acc[t][r]) | ((uint)f2bf(acc[t + 4][r]) << 16);
                *reinterpret_cast<uint*>(H + (size_t)m * 256 + c * 4 + hb) = pk;
            }
        }
    }
}

// ---------------- edge weights: w = exp(lrelu(a_src[s]+a_dst[d])) -----------
// No max-subtraction: logits bounded (|e| ~ O(10)), f32 exp safe; alpha = w/sum(w)
// is mathematically identical to the max-subtracted form.
__global__ __launch_bounds__(256) void ew_kernel(const float* __restrict__ a_src,
                                                 const float* __restrict__ a_dst,
                                                 const int* __restrict__ sorted_src,
                                                 const int* __restrict__ sorted_dst,
                                                 float* __restrict__ ew, int E) {
    int j = blockIdx.x * 256 + threadIdx.x;
    if (j >= E) return;
    int s = sorted_src[j], d = sorted_dst[j];
    float4 as_ = *reinterpret_cast<const float4*>(a_src + (size_t)s * 4);
    float4 ad_ = *reinterpret_cast<const float4*>(a_dst + (size_t)d * 4);
    float4 w;
    w.x = __expf(lrelu(as_.x + ad_.x));
    w.y = __expf(lrelu(as_.y + ad_.y));
    w.z = __expf(lrelu(as_.z + ad_.z));
    w.w = __expf(lrelu(as_.w + ad_.w));
    *reinterpret_cast<float4*>(ew + (size_t)j * 4) = w;
}

// ---------------- weighted gather, one wave per node ------------------------
// R8-proven structure (precomputed ew, scalar metadata via readfirstlane'd
// node id, weighted accumulate) with ONE delta: 16-edge groups -- all 16
// H-row gathers issued back-to-back (2x memory-level parallelism per wave vs
// 8-deep), weights still scalar s_loads. Tail groups gate gathers/ACCs with a
// wave-uniform branch (beyond-end indices are real random rows -> wasted HBM
// fetch if ungated). Over-read safety: sorted->sortedd and ew->a_src are
// contiguous in the workspace; max over-read 15 slots.
// NOTE: macro params named W_/V_ to avoid the preprocessor substituting the
// parameter name inside swizzle members (.w).
#define AGG_ACC(W_, V_)                                                     \
    do {                                                                    \
        a0 += (W_).x * bflo((V_).x); a1 += (W_).y * bfhi((V_).x);           \
        a2 += (W_).z * bflo((V_).y); a3 += (W_).w * bfhi((V_).y);           \
        dp0 += (W_).x; dp1 += (W_).y; dp2 += (W_).z; dp3 += (W_).w;         \
    } while (0)

__global__ __launch_bounds__(256) void agg_kernel(const ushort* __restrict__ H,
                                                  const float* __restrict__ a_src,
                                                  const float* __restrict__ a_dst,
                                                  const int* __restrict__ row_ptr,
                                                  const int* __restrict__ sorted_src,
                                                  const float* __restrict__ ew,
                                                  const float* __restrict__ bias,
                                                  float* __restrict__ out, int N) {
    const int lane = threadIdx.x & 63;
    const int i = __builtin_amdgcn_readfirstlane(blockIdx.x * 4 + (threadIdx.x >> 6));
    if (i >= N) return;
    const float4 asv = *reinterpret_cast<const float4*>(a_src + (size_t)i * 4);
    const float4 adv = *reinterpret_cast<const float4*>(a_dst + (size_t)i * 4);
    const float ws0 = __expf(lrelu(asv.x + adv.x)), ws1 = __expf(lrelu(asv.y + adv.y));
    const float ws2 = __expf(lrelu(asv.z + adv.z)), ws3 = __expf(lrelu(asv.w + adv.w));
    const int start = row_ptr[i], end = row_ptr[i + 1];

    float a0 = 0.f, a1 = 0.f, a2 = 0.f, a3 = 0.f;
    float dp0 = 0.f, dp1 = 0.f, dp2 = 0.f, dp3 = 0.f;
    const ushort* __restrict__ Hl = H + lane * 4;   // this lane's channel slice

    for (int j0 = start; j0 < end; j0 += 16) {
        int s[16];
        #pragma unroll
        for (int k = 0; k < 16; k++) s[k] = sorted_src[j0 + k];   // scalar loads
        if (j0 + 16 <= end) {
            uintx2 hv[16];
            #pragma unroll
            for (int k = 0; k < 16; k++)                          // 16 gathers in flight
                hv[k] = *reinterpret_cast<const uintx2*>(Hl + (size_t)s[k] * 256);
            floatx4 w[16];
            #pragma unroll
            for (int k = 0; k < 16; k++)                          // scalar dwordx16 loads
                w[k] = *reinterpret_cast<const floatx4*>(ew + (size_t)(j0 + k) * 4);
            #pragma unroll
            for (int k = 0; k < 16; k++) AGG_ACC(w[k], hv[k]);
        } else {
            const int nv = end - j0;                              // 1..15 valid
            uintx2 hv[16];
            #pragma unroll
            for (int k = 0; k < 16; k++)
                if (k < nv)                                       // uniform gate
                    hv[k] = *reinterpret_cast<const uintx2*>(Hl + (size_t)s[k] * 256);
            floatx4 w[16];
            #pragma unroll
            for (int k = 0; k < 16; k++)
                if (k < nv)
                    w[k] = *reinterpret_cast<const floatx4*>(ew + (size_t)(j0 + k) * 4);
            #pragma unroll
            for (int k = 0; k < 16; k++)
                if (k < nv) AGG_ACC(w[k], hv[k]);
        }
    }
    // self loop
    {
        uintx2 hv = *reinterpret_cast<const uintx2*>(Hl + (size_t)i * 256);
        a0 += ws0 * bflo(hv.x); a1 += ws1 * bfhi(hv.x);
        a2 += ws2 * bflo(hv.y); a3 += ws3 * bfhi(hv.y);
    }
    const float r0 = 1.f / (dp0 + ws0 + 1e-16f), r1 = 1.f / (dp1 + ws1 + 1e-16f);
    const float r2 = 1.f / (dp2 + ws2 + 1e-16f), r3 = 1.f / (dp3 + ws3 + 1e-16f);
    // out[i*256 + h*64 + c], c = lane; nontemporal: don't evict H from L2
    float* op = out + (size_t)i * 256 + lane;
    float v;
    v = a0 * r0 + bias[lane];        v = (v > 0.f) ? v : expm1f(v);
    __builtin_nontemporal_store(v, op);
    v = a1 * r1 + bias[64 + lane];   v = (v > 0.f) ? v : expm1f(v);
    __builtin_nontemporal_store(v, op + 64);
    v = a2 * r2 + bias[128 + lane];  v = (v > 0.f) ? v : expm1f(v);
    __builtin_nontemporal_store(v, op + 128);
    v = a3 * r3 + bias[192 + lane];  v = (v > 0.f) ? v : expm1f(v);
    __builtin_nontemporal_store(v, op + 192);
}

extern "C" void kernel_launch(void* const* d_in, const int* in_sizes, int n_in,
                              void* d_out, int out_size, void* d_ws, size_t ws_size,
                              hipStream_t stream) {
    const float* x      = (const float*)d_in[0];
    const int*   eidx   = (const int*)d_in[1];
    const float* W1     = (const float*)d_in[2];
    const float* att_s1 = (const float*)d_in[3];
    const float* att_d1 = (const float*)d_in[4];
    const float* b1     = (const float*)d_in[5];
    const float* W2     = (const float*)d_in[6];
    const float* att_s2 = (const float*)d_in[7];
    const float* att_d2 = (const float*)d_in[8];
    const float* b2     = (const float*)d_in[9];
    float* out = (float*)d_out;

    const int N = N_NODES, E = N_EDGES;
    char* ws = (char*)d_ws;
    size_t off = 0;
    auto alloc = [&](size_t bytes) -> void* {
        void* p = ws + off;
        off += (bytes + 255) & ~(size_t)255;
        return p;
    };
    // NOTE: agg_kernel's tail over-read (<=15 slots) relies on (ew -> a_src)
    // and (sorted -> sortedd) being contiguous: E*16 and E*4 are 256-aligned.
    ushort* h       = (ushort*)alloc((size_t)N * 256 * sizeof(ushort));  // 25.6 MB
    float*  ew      = (float*) alloc((size_t)E * 4 * sizeof(float));     // 12.8 MB
    float*  a_src   = (float*) alloc((size_t)N * 4 * sizeof(float));
    float*  a_dst   = (float*) alloc((size_t)N * 4 * sizeof(float));
    int*    cnt     = (int*)   alloc((size_t)N * sizeof(int));
    int*    row_ptr = (int*)   alloc((size_t)(N + 1) * sizeof(int));
    int*    row_tmp = (int*)   alloc((size_t)N * sizeof(int));
    int*    sorted  = (int*)   alloc((size_t)E * sizeof(int));
    int*    sortedd = (int*)   alloc((size_t)E * sizeof(int));
    int*    excl    = (int*)   alloc((size_t)N * sizeof(int));
    int*    partial = (int*)   alloc(256 * sizeof(int));
    ushort* Wt1_hi  = (ushort*)alloc(272 * 256 * sizeof(ushort));   // 256 W^T + 8 att + 8 zero
    ushort* Wt1_lo  = (ushort*)alloc(272 * 256 * sizeof(ushort));
    ushort* Wt2_hi  = (ushort*)alloc(272 * 256 * sizeof(ushort));
    ushort* Wt2_lo  = (ushort*)alloc(272 * 256 * sizeof(ushort));
    float*  x2      = out;   // layer-1 f32 activations live in d_out, overwritten by layer 2
    (void)ws_size; (void)in_sizes; (void)n_in; (void)out_size;

    const int* e_src = eidx;
    const int* e_dst = eidx + E;
    const int nsb = (N + 255) / 256;   // 196 scan blocks
    const int neb = (E + 255) / 256;

    prep_w<<<512, 320, 0, stream>>>(W1, W2, att_s1, att_d1, att_s2, att_d2,
                                    Wt1_hi, Wt1_lo, Wt2_hi, Wt2_lo);
    hipMemsetAsync(cnt, 0, N * sizeof(int), stream);
    deg_kernel<<<neb, 256, 0, stream>>>(e_dst, cnt, E);
    scan1_kernel<<<nsb, 256, 0, stream>>>(cnt, excl, partial, N);
    scan2_kernel<<<1, 256, 0, stream>>>(partial, nsb);
    scan3_kernel<<<nsb, 256, 0, stream>>>(excl, partial, row_ptr, row_tmp, N);
    scatter_kernel<<<neb, 256, 0, stream>>>(e_src, e_dst, row_tmp, sorted, sortedd, E);

    dim3 ggrid((N + 63) / 64, 2);  // 782 x 2
    int nblk = (N + 3) / 4;        // 12500
    // layer 1
    gemm_att_kernel<<<ggrid, 256, 0, stream>>>(x, Wt1_hi, Wt1_lo, att_s1, att_d1,
                                               h, a_src, a_dst, N);
    ew_kernel<<<neb, 256, 0, stream>>>(a_src, a_dst, sorted, sortedd, ew, E);
    agg_kernel<<<nblk, 256, 0, stream>>>(h, a_src, a_dst, row_ptr, sorted, ew, b1, x2, N);
    // layer 2
    gemm_att_kernel<<<ggrid, 256, 0, stream>>>(x2, Wt2_hi, Wt2_lo, att_s2, att_d2,
                                               h, a_src, a_dst, N);
    ew_kernel<<<neb, 256, 0, stream>>>(a_src, a_dst, sorted, sortedd, ew, E);
    agg_kernel<<<nblk, 256, 0, stream>>>(h, a_src, a_dst, row_ptr, sorted, ew, b2, out, N);
}

// Round 11
// 471.828 us; speedup vs baseline: 1.0584x; 1.0584x over previous
//
#include <hip/hip_runtime.h>
#include <hip/hip_bf16.h>

#define N_NODES 50000
#define N_EDGES 800000
// HEADS=4, OUT_CH=64, F=256 hard-coded. All harness I/O float32.
// Internal H layout INTERLEAVED: H[node*256 + c*4 + h]  (c=channel 0..63, h=head 0..3)

typedef __attribute__((ext_vector_type(8))) short short8;   // 8 bf16 = 4 VGPRs (MFMA A/B frag)
typedef __attribute__((ext_vector_type(4))) float floatx4;  // MFMA C/D frag
typedef __attribute__((ext_vector_type(2))) uint uintx2;

__device__ __forceinline__ ushort f2bf(float f) {           // RNE f32->bf16 bits
    uint u = __float_as_uint(f);
    uint r = u + 0x7FFFu + ((u >> 16) & 1u);
    return (ushort)(r >> 16);
}
__device__ __forceinline__ float bfu2f(ushort h) {
    return __uint_as_float(((uint)h) << 16);
}
__device__ __forceinline__ float bflo(uint u) { return __uint_as_float(u << 16); }
__device__ __forceinline__ float bfhi(uint u) { return __uint_as_float(u & 0xffff0000u); }
__device__ __forceinline__ float lrelu(float e) { return e >= 0.f ? e : 0.2f * e; }

// ---------------- CSR build (dst-sorted incoming edge lists) ----------------
__global__ void deg_kernel(const int* __restrict__ dst, int* __restrict__ cnt, int E) {
    int i = blockIdx.x * blockDim.x + threadIdx.x;
    if (i < E) atomicAdd(&cnt[dst[i]], 1);
}

__global__ __launch_bounds__(256) void scan1_kernel(const int* __restrict__ cnt,
                                                    int* __restrict__ excl,
                                                    int* __restrict__ partial, int n) {
    __shared__ int sd[256];
    int tid = threadIdx.x;
    int i = blockIdx.x * 256 + tid;
    int v = (i < n) ? cnt[i] : 0;
    sd[tid] = v;
    __syncthreads();
    #pragma unroll
    for (int off = 1; off < 256; off <<= 1) {
        int t = (tid >= off) ? sd[tid - off] : 0;
        __syncthreads();
        sd[tid] += t;
        __syncthreads();
    }
    if (i < n) excl[i] = sd[tid] - v;
    if (tid == 255) partial[blockIdx.x] = sd[255];
}

__global__ __launch_bounds__(256) void scan2_kernel(int* __restrict__ partial, int nb) {
    __shared__ int sd[256];
    int tid = threadIdx.x;
    int v = (tid < nb) ? partial[tid] : 0;
    sd[tid] = v;
    __syncthreads();
    #pragma unroll
    for (int off = 1; off < 256; off <<= 1) {
        int t = (tid >= off) ? sd[tid - off] : 0;
        __syncthreads();
        sd[tid] += t;
        __syncthreads();
    }
    if (tid < nb) partial[tid] = sd[tid] - v;   // exclusive
}

__global__ __launch_bounds__(256) void scan3_kernel(const int* __restrict__ excl,
                                                    const int* __restrict__ partial,
                                                    int* __restrict__ row_ptr,
                                                    int* __restrict__ row_tmp, int n) {
    int i = blockIdx.x * 256 + threadIdx.x;
    if (i < n) {
        int v = excl[i] + partial[blockIdx.x];
        row_ptr[i] = v;
        row_tmp[i] = v;
    }
    if (i == 0) row_ptr[n] = N_EDGES;
}

__global__ void scatter_kernel(const int* __restrict__ src, const int* __restrict__ dst,
                               int* __restrict__ row_tmp, int* __restrict__ sorted_src,
                               int* __restrict__ sorted_dst, int E) {
    int i = blockIdx.x * blockDim.x + threadIdx.x;
    if (i < E) {
        int d = dst[i];
        int p = atomicAdd(&row_tmp[d], 1);
        sorted_src[p] = src[i];
        sorted_dst[p] = d;
    }
}

// ------ W prep: transpose + bf16 hi/lo split (+ unused fused att rows) ------
__global__ __launch_bounds__(320) void prep_w(const float* __restrict__ W1,
                                              const float* __restrict__ W2,
                                              const float* __restrict__ as1,
                                              const float* __restrict__ ad1,
                                              const float* __restrict__ as2,
                                              const float* __restrict__ ad2,
                                              ushort* __restrict__ Wt1_hi,
                                              ushort* __restrict__ Wt1_lo,
                                              ushort* __restrict__ Wt2_hi,
                                              ushort* __restrict__ Wt2_lo) {
    int t = threadIdx.x, k = blockIdx.x & 255;
    int l1 = (blockIdx.x < 256);
    const float* W = l1 ? W1 : W2;
    const float* as_ = l1 ? as1 : as2;
    const float* ad_ = l1 ? ad1 : ad2;
    ushort* Wh = l1 ? Wt1_hi : Wt2_hi;
    ushort* Wl = l1 ? Wt1_lo : Wt2_lo;
    if (t < 256) {
        float v = W[k * 256 + t];
        ushort hb = f2bf(v);
        Wh[t * 256 + k] = hb;
        Wl[t * 256 + k] = f2bf(v - bfu2f(hb));
    } else if (t < 264) {
        int j = t - 256;
        int h = j & 3;
        const float* vec = (j < 4) ? as_ : ad_;
        float acc = 0.f;
        for (int c = 0; c < 64; c++) acc += W[k * 256 + h * 64 + c] * vec[h * 64 + c];
        ushort hb = f2bf(acc);
        Wh[t * 256 + k] = hb;
        Wl[t * 256 + k] = f2bf(acc - bfu2f(hb));
    } else if (t < 272) {
        Wh[t * 256 + k] = 0;
        Wl[t * 256 + k] = 0;
    }
}

// ------- GEMM + fused attention logits: FULL-WIDTH, DBUF + RAW BARRIERS -----
// Block: 64 rows x 256 cols, 4 waves; wave w owns rows [16w,16w+16) x all 256
// cols (16 tiles). A fetched + converted ONCE per block (was twice with the
// col-split). R8-proven schedule: one raw s_barrier + lgkmcnt(0) per k-step,
// W(t+1) in regs + A(t+2) loads in flight ACROSS barriers. Do NOT use
// __syncthreads -- hipcc adds a vmcnt(0) drain that kills the pipeline (m97).
// LDS 80 KB -> 2 blocks/CU. H stored packed: tiles {cc,cc+4,cc+8,cc+12} hold
// heads 0-3 of channel cc*16+l16 in the same lane -> one 8-B uintx2 store.
__global__ __launch_bounds__(256) void gemm_att_kernel(const float* __restrict__ A,
                                                       const ushort* __restrict__ Wt_hi,
                                                       const ushort* __restrict__ Wt_lo,
                                                       const float* __restrict__ att_s,
                                                       const float* __restrict__ att_d,
                                                       ushort* __restrict__ H,
                                                       float* __restrict__ a_src,
                                                       float* __restrict__ a_dst, int M) {
    const int ROWP = 40;
    __shared__ ushort hi_s[2][256 * ROWP];   // 2 x 20 KB
    __shared__ ushort lo_s[2][256 * ROWP];   // 2 x 20 KB
    const int tid = threadIdx.x;
    const int wave = tid >> 6, lane = tid & 63;
    const int quad = lane >> 4, l16 = lane & 15;
    const int brow = blockIdx.x * 64;
    const int mrow = brow + wave * 16 + l16;
    const int mload = (mrow < M) ? mrow : (M - 1);

    floatx4 acc[16];
    #pragma unroll
    for (int t = 0; t < 16; t++) acc[t] = (floatx4){0.f, 0.f, 0.f, 0.f};

    // staging: thread tid stages col tid, BOTH hi and lo planes
    const ushort* gWh = Wt_hi + (size_t)tid * 256;
    const ushort* gWl = Wt_lo + (size_t)tid * 256;
    ushort* sH0 = &hi_s[0][0] + tid * ROWP;
    ushort* sH1 = &hi_s[1][0] + tid * ROWP;
    ushort* sL0 = &lo_s[0][0] + tid * ROWP;
    ushort* sL1 = &lo_s[1][0] + tid * ROWP;

    const float* ap = A + (size_t)mload * 256 + quad * 8;

    // prologue: W(0) -> regs -> buf0; A(0), A(1) -> regs
    short8 whreg[4], wlreg[4];
    #pragma unroll
    for (int i = 0; i < 4; i++) {
        whreg[i] = *reinterpret_cast<const short8*>(gWh + i * 8);
        wlreg[i] = *reinterpret_cast<const short8*>(gWl + i * 8);
    }
    float4 af0[2], af1[2];
    af0[0] = *reinterpret_cast<const float4*>(ap);
    af1[0] = *reinterpret_cast<const float4*>(ap + 4);
    af0[1] = *reinterpret_cast<const float4*>(ap + 32);
    af1[1] = *reinterpret_cast<const float4*>(ap + 36);
    #pragma unroll
    for (int i = 0; i < 4; i++) {
        *reinterpret_cast<short8*>(sH0 + i * 8) = whreg[i];
        *reinterpret_cast<short8*>(sL0 + i * 8) = wlreg[i];
    }
    asm volatile("s_waitcnt lgkmcnt(0)" ::: "memory");
    __builtin_amdgcn_s_barrier();

    #pragma unroll
    for (int t = 0; t < 8; t++) {
        const int cur = t & 1;
        if (t < 7) {                      // issue W(t+1): lands during this step
            #pragma unroll
            for (int i = 0; i < 4; i++) {
                whreg[i] = *reinterpret_cast<const short8*>(gWh + (t + 1) * 32 + i * 8);
                wlreg[i] = *reinterpret_cast<const short8*>(gWl + (t + 1) * 32 + i * 8);
            }
        }
        // convert A(t) -> bf16 hi/lo (ONCE for all 16 tiles)
        float av[8] = {af0[cur].x, af0[cur].y, af0[cur].z, af0[cur].w,
                       af1[cur].x, af1[cur].y, af1[cur].z, af1[cur].w};
        short8 a_hi, a_lo;
        #pragma unroll
        for (int j = 0; j < 8; j++) {
            ushort hb = f2bf(av[j]);
            a_hi[j] = (short)hb;
            a_lo[j] = (short)f2bf(av[j] - bfu2f(hb));
        }
        if (t < 6) {                      // A(t+2): 2-deep, crosses one raw barrier
            af0[cur] = *reinterpret_cast<const float4*>(ap + (t + 2) * 32);
            af1[cur] = *reinterpret_cast<const float4*>(ap + (t + 2) * 32 + 4);
        }
        const ushort* rh = (cur == 0) ? &hi_s[0][0] : &hi_s[1][0];
        const ushort* rl = (cur == 0) ? &lo_s[0][0] : &lo_s[1][0];
        #pragma unroll
        for (int tt = 0; tt < 16; tt++) {
            int roff = (tt * 16 + l16) * ROWP + quad * 8;
            short8 b_hi = *reinterpret_cast<const short8*>(rh + roff);
            short8 b_lo = *reinterpret_cast<const short8*>(rl + roff);
            acc[tt] = __builtin_amdgcn_mfma_f32_16x16x32_bf16(a_hi, b_hi, acc[tt], 0, 0, 0);
            acc[tt] = __builtin_amdgcn_mfma_f32_16x16x32_bf16(a_hi, b_lo, acc[tt], 0, 0, 0);
            acc[tt] = __builtin_amdgcn_mfma_f32_16x16x32_bf16(a_lo, b_hi, acc[tt], 0, 0, 0);
        }
        if (t < 7) {                      // stage W(t+1) into the other buffer
            ushort* dH = cur ? sH0 : sH1;
            ushort* dL = cur ? sL0 : sL1;
            #pragma unroll
            for (int i = 0; i < 4; i++) {
                *reinterpret_cast<short8*>(dH + i * 8) = whreg[i];
                *reinterpret_cast<short8*>(dL + i * 8) = wlreg[i];
            }
        }
        asm volatile("s_waitcnt lgkmcnt(0)" ::: "memory");
        __builtin_amdgcn_s_barrier();
    }
    // fused attention-logit partials: tile t -> head t>>2
    float ps[4][4] = {}, pd[4][4] = {};
    #pragma unroll
    for (int t = 0; t < 16; t++) {
        int hh = t >> 2;
        float as_v = att_s[t * 16 + l16];
        float ad_v = att_d[t * 16 + l16];
        #pragma unroll
        for (int r = 0; r < 4; r++) {
            ps[hh][r] += acc[t][r] * as_v;
            pd[hh][r] += acc[t][r] * ad_v;
        }
    }
    #pragma unroll
    for (int off = 1; off < 16; off <<= 1) {
        #pragma unroll
        for (int hh = 0; hh < 4; hh++)
            #pragma unroll
            for (int r = 0; r < 4; r++) {
                ps[hh][r] += __shfl_xor(ps[hh][r], off, 64);
                pd[hh][r] += __shfl_xor(pd[hh][r], off, 64);
            }
    }
    if (l16 == 0) {
        #pragma unroll
        for (int r = 0; r < 4; r++) {
            int m = brow + wave * 16 + quad * 4 + r;
            if (m < M) {
                #pragma unroll
                for (int hh = 0; hh < 4; hh++) {
                    a_src[m * 4 + hh] = ps[hh][r];
                    a_dst[m * 4 + hh] = pd[hh][r];
                }
            }
        }
    }
    // store bf16 H, interleaved (c*4 + h), fully packed: tiles cc,cc+4,cc+8,
    // cc+12 share c = cc*16+l16 and hold heads 0..3 -> one uintx2 store.
    #pragma unroll
    for (int cc = 0; cc < 4; cc++) {
        #pragma unroll
        for (int r = 0; r < 4; r++) {
            int m = brow + wave * 16 + quad * 4 + r;
            if (m < M) {
                uintx2 pk;
                pk.x = (uint)f2bf(acc[cc][r])     | ((uint)f2bf(acc[cc + 4][r]) << 16);
                pk.y = (uint)f2bf(acc[cc + 8][r]) | ((uint)f2bf(acc[cc + 12][r]) << 16);
                *reinterpret_cast<uintx2*>(H + (size_t)m * 256 + (cc * 16 + l16) * 4) = pk;
            }
        }
    }
}

// ---------------- edge weights: w = exp(lrelu(a_src[s]+a_dst[d])) -----------
// No max-subtraction: logits bounded (|e| ~ O(10)), f32 exp safe; alpha = w/sum(w)
// is mathematically identical to the max-subtracted form.
__global__ __launch_bounds__(256) void ew_kernel(const float* __restrict__ a_src,
                                                 const float* __restrict__ a_dst,
                                                 const int* __restrict__ sorted_src,
                                                 const int* __restrict__ sorted_dst,
                                                 float* __restrict__ ew, int E) {
    int j = blockIdx.x * 256 + threadIdx.x;
    if (j >= E) return;
    int s = sorted_src[j], d = sorted_dst[j];
    float4 as_ = *reinterpret_cast<const float4*>(a_src + (size_t)s * 4);
    float4 ad_ = *reinterpret_cast<const float4*>(a_dst + (size_t)d * 4);
    float4 w;
    w.x = __expf(lrelu(as_.x + ad_.x));
    w.y = __expf(lrelu(as_.y + ad_.y));
    w.z = __expf(lrelu(as_.z + ad_.z));
    w.w = __expf(lrelu(as_.w + ad_.w));
    *reinterpret_cast<float4*>(ew + (size_t)j * 4) = w;
}

// ---------------- weighted gather, one wave per node (R8-exact) -------------
// All 64 lanes on ONE edge: lane = channel c, uint2 = heads 0..3 bf16.
// Node index forced wave-uniform via readfirstlane so the per-edge metadata
// (sorted_src, ew) compiles to scalar loads; 8 H-row gathers in flight.
// 8-deep UNGATED groups are the measured optimum (8-deep=67us beats fused=82
// and 16-deep-gated=91): tail over-gather wastes ~3% of bytes but keeps the
// load issue branch-free. Over-read safety: sorted->sortedd and ew->a_src
// are contiguous in the workspace (garbage indices still valid node ids).
// NOTE: macro params named W_/V_ to avoid the preprocessor substituting the
// parameter name inside swizzle members (.w).
#define AGG_ACC(W_, V_)                                                     \
    do {                                                                    \
        a0 += (W_).x * bflo((V_).x); a1 += (W_).y * bfhi((V_).x);           \
        a2 += (W_).z * bflo((V_).y); a3 += (W_).w * bfhi((V_).y);           \
        dp0 += (W_).x; dp1 += (W_).y; dp2 += (W_).z; dp3 += (W_).w;         \
    } while (0)

__global__ __launch_bounds__(256) void agg_kernel(const ushort* __restrict__ H,
                                                  const float* __restrict__ a_src,
                                                  const float* __restrict__ a_dst,
                                                  const int* __restrict__ row_ptr,
                                                  const int* __restrict__ sorted_src,
                                                  const float* __restrict__ ew,
                                                  const float* __restrict__ bias,
                                                  float* __restrict__ out, int N) {
    const int lane = threadIdx.x & 63;
    const int i = __builtin_amdgcn_readfirstlane(blockIdx.x * 4 + (threadIdx.x >> 6));
    if (i >= N) return;
    const float4 asv = *reinterpret_cast<const float4*>(a_src + (size_t)i * 4);
    const float4 adv = *reinterpret_cast<const float4*>(a_dst + (size_t)i * 4);
    const float ws0 = __expf(lrelu(asv.x + adv.x)), ws1 = __expf(lrelu(asv.y + adv.y));
    const float ws2 = __expf(lrelu(asv.z + adv.z)), ws3 = __expf(lrelu(asv.w + adv.w));
    const int start = row_ptr[i], end = row_ptr[i + 1];

    float a0 = 0.f, a1 = 0.f, a2 = 0.f, a3 = 0.f;
    float dp0 = 0.f, dp1 = 0.f, dp2 = 0.f, dp3 = 0.f;
    const ushort* __restrict__ Hl = H + lane * 4;   // this lane's channel slice

    for (int j0 = start; j0 < end; j0 += 8) {
        int s[8];
        #pragma unroll
        for (int k = 0; k < 8; k++) s[k] = sorted_src[j0 + k];        // s_load_dwordx8
        floatx4 w[8];
        #pragma unroll
        for (int k = 0; k < 8; k++)                                   // 2x s_load_dwordx16
            w[k] = *reinterpret_cast<const floatx4*>(ew + (size_t)(j0 + k) * 4);
        uintx2 hv[8];
        #pragma unroll
        for (int k = 0; k < 8; k++)                                   // 8 gathers in flight
            hv[k] = *reinterpret_cast<const uintx2*>(Hl + (size_t)s[k] * 256);
        if (j0 + 8 <= end) {
            #pragma unroll
            for (int k = 0; k < 8; k++) AGG_ACC(w[k], hv[k]);
        } else {
            #pragma unroll
            for (int k = 0; k < 8; k++)
                if (j0 + k < end) AGG_ACC(w[k], hv[k]);               // uniform branch
        }
    }
    // self loop
    {
        uintx2 hv = *reinterpret_cast<const uintx2*>(Hl + (size_t)i * 256);
        a0 += ws0 * bflo(hv.x); a1 += ws1 * bfhi(hv.x);
        a2 += ws2 * bflo(hv.y); a3 += ws3 * bfhi(hv.y);
    }
    const float r0 = 1.f / (dp0 + ws0 + 1e-16f), r1 = 1.f / (dp1 + ws1 + 1e-16f);
    const float r2 = 1.f / (dp2 + ws2 + 1e-16f), r3 = 1.f / (dp3 + ws3 + 1e-16f);
    // out[i*256 + h*64 + c], c = lane; nontemporal: don't evict H from L2
    float* op = out + (size_t)i * 256 + lane;
    float v;
    v = a0 * r0 + bias[lane];        v = (v > 0.f) ? v : expm1f(v);
    __builtin_nontemporal_store(v, op);
    v = a1 * r1 + bias[64 + lane];   v = (v > 0.f) ? v : expm1f(v);
    __builtin_nontemporal_store(v, op + 64);
    v = a2 * r2 + bias[128 + lane];  v = (v > 0.f) ? v : expm1f(v);
    __builtin_nontemporal_store(v, op + 128);
    v = a3 * r3 + bias[192 + lane];  v = (v > 0.f) ? v : expm1f(v);
    __builtin_nontemporal_store(v, op + 192);
}

extern "C" void kernel_launch(void* const* d_in, const int* in_sizes, int n_in,
                              void* d_out, int out_size, void* d_ws, size_t ws_size,
                              hipStream_t stream) {
    const float* x      = (const float*)d_in[0];
    const int*   eidx   = (const int*)d_in[1];
    const float* W1     = (const float*)d_in[2];
    const float* att_s1 = (const float*)d_in[3];
    const float* att_d1 = (const float*)d_in[4];
    const float* b1     = (const float*)d_in[5];
    const float* W2     = (const float*)d_in[6];
    const float* att_s2 = (const float*)d_in[7];
    const float* att_d2 = (const float*)d_in[8];
    const float* b2     = (const float*)d_in[9];
    float* out = (float*)d_out;

    const int N = N_NODES, E = N_EDGES;
    char* ws = (char*)d_ws;
    size_t off = 0;
    auto alloc = [&](size_t bytes) -> void* {
        void* p = ws + off;
        off += (bytes + 255) & ~(size_t)255;
        return p;
    };
    // NOTE: agg_kernel's tail over-read (<=7 slots) relies on (ew -> a_src)
    // and (sorted -> sortedd) being contiguous: E*16 and E*4 are 256-aligned.
    ushort* h       = (ushort*)alloc((size_t)N * 256 * sizeof(ushort));  // 25.6 MB
    float*  ew      = (float*) alloc((size_t)E * 4 * sizeof(float));     // 12.8 MB
    float*  a_src   = (float*) alloc((size_t)N * 4 * sizeof(float));
    float*  a_dst   = (float*) alloc((size_t)N * 4 * sizeof(float));
    int*    cnt     = (int*)   alloc((size_t)N * sizeof(int));
    int*    row_ptr = (int*)   alloc((size_t)(N + 1) * sizeof(int));
    int*    row_tmp = (int*)   alloc((size_t)N * sizeof(int));
    int*    sorted  = (int*)   alloc((size_t)E * sizeof(int));
    int*    sortedd = (int*)   alloc((size_t)E * sizeof(int));
    int*    excl    = (int*)   alloc((size_t)N * sizeof(int));
    int*    partial = (int*)   alloc(256 * sizeof(int));
    ushort* Wt1_hi  = (ushort*)alloc(272 * 256 * sizeof(ushort));   // 256 W^T + 8 att + 8 zero
    ushort* Wt1_lo  = (ushort*)alloc(272 * 256 * sizeof(ushort));
    ushort* Wt2_hi  = (ushort*)alloc(272 * 256 * sizeof(ushort));
    ushort* Wt2_lo  = (ushort*)alloc(272 * 256 * sizeof(ushort));
    float*  x2      = out;   // layer-1 f32 activations live in d_out, overwritten by layer 2
    (void)ws_size; (void)in_sizes; (void)n_in; (void)out_size;

    const int* e_src = eidx;
    const int* e_dst = eidx + E;
    const int nsb = (N + 255) / 256;   // 196 scan blocks
    const int neb = (E + 255) / 256;

    prep_w<<<512, 320, 0, stream>>>(W1, W2, att_s1, att_d1, att_s2, att_d2,
                                    Wt1_hi, Wt1_lo, Wt2_hi, Wt2_lo);
    hipMemsetAsync(cnt, 0, N * sizeof(int), stream);
    deg_kernel<<<neb, 256, 0, stream>>>(e_dst, cnt, E);
    scan1_kernel<<<nsb, 256, 0, stream>>>(cnt, excl, partial, N);
    scan2_kernel<<<1, 256, 0, stream>>>(partial, nsb);
    scan3_kernel<<<nsb, 256, 0, stream>>>(excl, partial, row_ptr, row_tmp, N);
    scatter_kernel<<<neb, 256, 0, stream>>>(e_src, e_dst, row_tmp, sorted, sortedd, E);

    int ggrid = (N + 63) / 64;     // 782 blocks, full 256-col width
    int nblk = (N + 3) / 4;        // 12500
    // layer 1
    gemm_att_kernel<<<ggrid, 256, 0, stream>>>(x, Wt1_hi, Wt1_lo, att_s1, att_d1,
                                               h, a_src, a_dst, N);
    ew_kernel<<<neb, 256, 0, stream>>>(a_src, a_dst, sorted, sortedd, ew, E);
    agg_kernel<<<nblk, 256, 0, stream>>>(h, a_src, a_dst, row_ptr, sorted, ew, b1, x2, N);
    // layer 2
    gemm_att_kernel<<<ggrid, 256, 0, stream>>>(x2, Wt2_hi, Wt2_lo, att_s2, att_d2,
                                               h, a_src, a_dst, N);
    ew_kernel<<<neb, 256, 0, stream>>>(a_src, a_dst, sorted, sortedd, ew, E);
    agg_kernel<<<nblk, 256, 0, stream>>>(h, a_src, a_dst, row_ptr, sorted, ew, b2, out, N);
}

// Round 12
// 435.675 us; speedup vs baseline: 1.1462x; 1.0830x over previous
//
#include <hip/hip_runtime.h>
#include <hip/hip_bf16.h>

#define N_NODES 50000
#define N_EDGES 800000
// HEADS=4, OUT_CH=64, F=256 hard-coded. All harness I/O float32.
// Internal H layout INTERLEAVED: H[node*256 + c*4 + h]  (c=channel 0..63, h=head 0..3)

typedef __attribute__((ext_vector_type(8))) short short8;   // 8 bf16 = 4 VGPRs (MFMA A/B frag)
typedef __attribute__((ext_vector_type(4))) float floatx4;  // MFMA C/D frag
typedef __attribute__((ext_vector_type(2))) uint uintx2;

__device__ __forceinline__ ushort f2bf(float f) {           // RNE f32->bf16 bits
    uint u = __float_as_uint(f);
    uint r = u + 0x7FFFu + ((u >> 16) & 1u);
    return (ushort)(r >> 16);
}
__device__ __forceinline__ float bfu2f(ushort h) {
    return __uint_as_float(((uint)h) << 16);
}
__device__ __forceinline__ float bflo(uint u) { return __uint_as_float(u << 16); }
__device__ __forceinline__ float bfhi(uint u) { return __uint_as_float(u & 0xffff0000u); }
__device__ __forceinline__ float lrelu(float e) { return e >= 0.f ? e : 0.2f * e; }

// ---------------- CSR build (dst-sorted incoming edge lists) ----------------
__global__ void deg_kernel(const int* __restrict__ dst, int* __restrict__ cnt, int E) {
    int i = blockIdx.x * blockDim.x + threadIdx.x;
    if (i < E) atomicAdd(&cnt[dst[i]], 1);
}

__global__ __launch_bounds__(256) void scan1_kernel(const int* __restrict__ cnt,
                                                    int* __restrict__ excl,
                                                    int* __restrict__ partial, int n) {
    __shared__ int sd[256];
    int tid = threadIdx.x;
    int i = blockIdx.x * 256 + tid;
    int v = (i < n) ? cnt[i] : 0;
    sd[tid] = v;
    __syncthreads();
    #pragma unroll
    for (int off = 1; off < 256; off <<= 1) {
        int t = (tid >= off) ? sd[tid - off] : 0;
        __syncthreads();
        sd[tid] += t;
        __syncthreads();
    }
    if (i < n) excl[i] = sd[tid] - v;
    if (tid == 255) partial[blockIdx.x] = sd[255];
}

__global__ __launch_bounds__(256) void scan2_kernel(int* __restrict__ partial, int nb) {
    __shared__ int sd[256];
    int tid = threadIdx.x;
    int v = (tid < nb) ? partial[tid] : 0;
    sd[tid] = v;
    __syncthreads();
    #pragma unroll
    for (int off = 1; off < 256; off <<= 1) {
        int t = (tid >= off) ? sd[tid - off] : 0;
        __syncthreads();
        sd[tid] += t;
        __syncthreads();
    }
    if (tid < nb) partial[tid] = sd[tid] - v;   // exclusive
}

__global__ __launch_bounds__(256) void scan3_kernel(const int* __restrict__ excl,
                                                    const int* __restrict__ partial,
                                                    int* __restrict__ row_ptr,
                                                    int* __restrict__ row_tmp, int n) {
    int i = blockIdx.x * 256 + threadIdx.x;
    if (i < n) {
        int v = excl[i] + partial[blockIdx.x];
        row_ptr[i] = v;
        row_tmp[i] = v;
    }
    if (i == 0) row_ptr[n] = N_EDGES;
}

__global__ void scatter_kernel(const int* __restrict__ src, const int* __restrict__ dst,
                               int* __restrict__ row_tmp, int* __restrict__ sorted_src,
                               int* __restrict__ sorted_dst, int E) {
    int i = blockIdx.x * blockDim.x + threadIdx.x;
    if (i < E) {
        int d = dst[i];
        int p = atomicAdd(&row_tmp[d], 1);
        sorted_src[p] = src[i];
        sorted_dst[p] = d;
    }
}

// ------ W prep: transpose + bf16 hi/lo split (+ unused fused att rows) ------
__global__ __launch_bounds__(320) void prep_w(const float* __restrict__ W1,
                                              const float* __restrict__ W2,
                                              const float* __restrict__ as1,
                                              const float* __restrict__ ad1,
                                              const float* __restrict__ as2,
                                              const float* __restrict__ ad2,
                                              ushort* __restrict__ Wt1_hi,
                                              ushort* __restrict__ Wt1_lo,
                                              ushort* __restrict__ Wt2_hi,
                                              ushort* __restrict__ Wt2_lo) {
    int t = threadIdx.x, k = blockIdx.x & 255;
    int l1 = (blockIdx.x < 256);
    const float* W = l1 ? W1 : W2;
    const float* as_ = l1 ? as1 : as2;
    const float* ad_ = l1 ? ad1 : ad2;
    ushort* Wh = l1 ? Wt1_hi : Wt2_hi;
    ushort* Wl = l1 ? Wt1_lo : Wt2_lo;
    if (t < 256) {
        float v = W[k * 256 + t];
        ushort hb = f2bf(v);
        Wh[t * 256 + k] = hb;
        Wl[t * 256 + k] = f2bf(v - bfu2f(hb));
    } else if (t < 264) {
        int j = t - 256;
        int h = j & 3;
        const float* vec = (j < 4) ? as_ : ad_;
        float acc = 0.f;
        for (int c = 0; c < 64; c++) acc += W[k * 256 + h * 64 + c] * vec[h * 64 + c];
        ushort hb = f2bf(acc);
        Wh[t * 256 + k] = hb;
        Wl[t * 256 + k] = f2bf(acc - bfu2f(hb));
    } else if (t < 272) {
        Wh[t * 256 + k] = 0;
        Wl[t * 256 + k] = 0;
    }
}

// ------- GEMM + fused attention logits, col-split, DBUF + RAW BARRIERS ------
// R8-proven schedule (one raw s_barrier + lgkmcnt(0) per k-step, W/A
// prefetched ACROSS barriers; never __syncthreads -- hipcc adds a vmcnt(0)
// drain there that kills the pipeline, m97). ONE delta vs R8: 128 rows per
// block (2 row-groups per wave) -- W-staging and barriers amortize over 2x
// the rows, MFMA per barrier-pair doubles (24->48/wave), LDS stays 40 KB
// (unlike the R11 full-width attempt whose 80 KB collapsed occupancy).
__global__ __launch_bounds__(256) void gemm_att_kernel(const float* __restrict__ A,
                                                       const ushort* __restrict__ Wt_hi,
                                                       const ushort* __restrict__ Wt_lo,
                                                       const float* __restrict__ att_s,
                                                       const float* __restrict__ att_d,
                                                       ushort* __restrict__ H,
                                                       float* __restrict__ a_src,
                                                       float* __restrict__ a_dst, int M) {
    const int ROWP = 40;
    __shared__ ushort hi_s[2][128 * ROWP];   // 2 x 10 KB
    __shared__ ushort lo_s[2][128 * ROWP];   // 2 x 10 KB
    const int tid = threadIdx.x;
    const int wave = tid >> 6, lane = tid & 63;
    const int quad = lane >> 4, l16 = lane & 15;
    const int brow = blockIdx.x * 128;
    const int coff = blockIdx.y * 128;    // column offset (also Wt row offset)

    floatx4 acc[2][8];
    #pragma unroll
    for (int rg = 0; rg < 2; rg++)
        #pragma unroll
        for (int t = 0; t < 8; t++) acc[rg][t] = (floatx4){0.f, 0.f, 0.f, 0.f};

    // staging role: threads 0-127 stage hi, 128-255 stage lo; col = tid&127
    const int scol = tid & 127;
    const ushort* gW = ((tid < 128) ? Wt_hi : Wt_lo) + (size_t)(coff + scol) * 256;
    ushort* sB0 = ((tid < 128) ? &hi_s[0][0] : &lo_s[0][0]) + scol * ROWP;
    ushort* sB1 = ((tid < 128) ? &hi_s[1][0] : &lo_s[1][0]) + scol * ROWP;

    const float* ap[2];
    #pragma unroll
    for (int rg = 0; rg < 2; rg++) {
        int mrow = brow + rg * 64 + wave * 16 + l16;
        int mload = (mrow < M) ? mrow : (M - 1);
        ap[rg] = A + (size_t)mload * 256 + quad * 8;
    }

    // prologue: W(0) -> regs -> buf0; A(0), A(1) -> regs (both row-groups)
    short8 wreg[4];
    #pragma unroll
    for (int i = 0; i < 4; i++)
        wreg[i] = *reinterpret_cast<const short8*>(gW + i * 8);
    float4 af0[2][2], af1[2][2];    // [buffer][row-group]
    #pragma unroll
    for (int rg = 0; rg < 2; rg++) {
        af0[0][rg] = *reinterpret_cast<const float4*>(ap[rg]);
        af1[0][rg] = *reinterpret_cast<const float4*>(ap[rg] + 4);
        af0[1][rg] = *reinterpret_cast<const float4*>(ap[rg] + 32);
        af1[1][rg] = *reinterpret_cast<const float4*>(ap[rg] + 36);
    }
    #pragma unroll
    for (int i = 0; i < 4; i++)
        *reinterpret_cast<short8*>(sB0 + i * 8) = wreg[i];
    asm volatile("s_waitcnt lgkmcnt(0)" ::: "memory");
    __builtin_amdgcn_s_barrier();

    #pragma unroll
    for (int t = 0; t < 8; t++) {
        const int cur = t & 1;
        if (t < 7) {                      // issue W(t+1): lands during this step
            #pragma unroll
            for (int i = 0; i < 4; i++)
                wreg[i] = *reinterpret_cast<const short8*>(gW + (t + 1) * 32 + i * 8);
        }
        // convert A(t) -> bf16 hi/lo, both row-groups
        short8 a_hi[2], a_lo[2];
        #pragma unroll
        for (int rg = 0; rg < 2; rg++) {
            float av[8] = {af0[cur][rg].x, af0[cur][rg].y, af0[cur][rg].z, af0[cur][rg].w,
                           af1[cur][rg].x, af1[cur][rg].y, af1[cur][rg].z, af1[cur][rg].w};
            #pragma unroll
            for (int j = 0; j < 8; j++) {
                ushort hb = f2bf(av[j]);
                a_hi[rg][j] = (short)hb;
                a_lo[rg][j] = (short)f2bf(av[j] - bfu2f(hb));
            }
        }
        if (t < 6) {                      // A(t+2): 2-deep, crosses one raw barrier
            #pragma unroll
            for (int rg = 0; rg < 2; rg++) {
                af0[cur][rg] = *reinterpret_cast<const float4*>(ap[rg] + (t + 2) * 32);
                af1[cur][rg] = *reinterpret_cast<const float4*>(ap[rg] + (t + 2) * 32 + 4);
            }
        }
        const ushort* rh = (cur == 0) ? &hi_s[0][0] : &hi_s[1][0];
        const ushort* rl = (cur == 0) ? &lo_s[0][0] : &lo_s[1][0];
        #pragma unroll
        for (int tt = 0; tt < 8; tt++) {
            int roff = (tt * 16 + l16) * ROWP + quad * 8;
            short8 b_hi = *reinterpret_cast<const short8*>(rh + roff);
            short8 b_lo = *reinterpret_cast<const short8*>(rl + roff);
            #pragma unroll
            for (int rg = 0; rg < 2; rg++) {
                acc[rg][tt] = __builtin_amdgcn_mfma_f32_16x16x32_bf16(a_hi[rg], b_hi, acc[rg][tt], 0, 0, 0);
                acc[rg][tt] = __builtin_amdgcn_mfma_f32_16x16x32_bf16(a_hi[rg], b_lo, acc[rg][tt], 0, 0, 0);
                acc[rg][tt] = __builtin_amdgcn_mfma_f32_16x16x32_bf16(a_lo[rg], b_hi, acc[rg][tt], 0, 0, 0);
            }
        }
        if (t < 7) {                      // stage W(t+1) into the other buffer
            ushort* sBn = cur ? sB0 : sB1;
            #pragma unroll
            for (int i = 0; i < 4; i++)
                *reinterpret_cast<short8*>(sBn + i * 8) = wreg[i];
        }
        asm volatile("s_waitcnt lgkmcnt(0)" ::: "memory");
        __builtin_amdgcn_s_barrier();
    }
    // fused attention-logit partials: tiles 0-3 -> head coff/64, 4-7 -> +1
    const int hb = blockIdx.y * 2;
    float ps[2][2][4] = {}, pd[2][2][4] = {};
    #pragma unroll
    for (int t = 0; t < 8; t++) {
        int hh = t >> 2;
        float as_v = att_s[coff + t * 16 + l16];
        float ad_v = att_d[coff + t * 16 + l16];
        #pragma unroll
        for (int rg = 0; rg < 2; rg++)
            #pragma unroll
            for (int r = 0; r < 4; r++) {
                ps[rg][hh][r] += acc[rg][t][r] * as_v;
                pd[rg][hh][r] += acc[rg][t][r] * ad_v;
            }
    }
    #pragma unroll
    for (int off = 1; off < 16; off <<= 1) {
        #pragma unroll
        for (int rg = 0; rg < 2; rg++)
            #pragma unroll
            for (int hh = 0; hh < 2; hh++)
                #pragma unroll
                for (int r = 0; r < 4; r++) {
                    ps[rg][hh][r] += __shfl_xor(ps[rg][hh][r], off, 64);
                    pd[rg][hh][r] += __shfl_xor(pd[rg][hh][r], off, 64);
                }
    }
    if (l16 == 0) {
        #pragma unroll
        for (int rg = 0; rg < 2; rg++)
            #pragma unroll
            for (int r = 0; r < 4; r++) {
                int m = brow + rg * 64 + wave * 16 + quad * 4 + r;
                if (m < M) {
                    #pragma unroll
                    for (int hh = 0; hh < 2; hh++) {
                        a_src[m * 4 + hb + hh] = ps[rg][hh][r];
                        a_dst[m * 4 + hb + hh] = pd[rg][hh][r];
                    }
                }
            }
    }
    // store bf16 H, interleaved (c*4 + h), packed head-pairs: tiles t and t+4
    // share c = t*16 + l16 and hold heads hb, hb+1 -> one uint store.
    #pragma unroll
    for (int rg = 0; rg < 2; rg++)
        #pragma unroll
        for (int t = 0; t < 4; t++) {
            int c = t * 16 + l16;
            #pragma unroll
            for (int r = 0; r < 4; r++) {
                int m = brow + rg * 64 + wave * 16 + quad * 4 + r;
                if (m < M) {
                    uint pk = (uint)f2bf(acc[rg][t][r]) | ((uint)f2bf(acc[rg][t + 4][r]) << 16);
                    *reinterpret_cast<uint*>(H + (size_t)m * 256 + c * 4 + hb) = pk;
                }
            }
        }
}

// ---------------- edge weights: w = exp(lrelu(a_src[s]+a_dst[d])) -----------
// No max-subtraction: logits bounded (|e| ~ O(10)), f32 exp safe; alpha = w/sum(w)
// is mathematically identical to the max-subtracted form.
__global__ __launch_bounds__(256) void ew_kernel(const float* __restrict__ a_src,
                                                 const float* __restrict__ a_dst,
                                                 const int* __restrict__ sorted_src,
                                                 const int* __restrict__ sorted_dst,
                                                 float* __restrict__ ew, int E) {
    int j = blockIdx.x * 256 + threadIdx.x;
    if (j >= E) return;
    int s = sorted_src[j], d = sorted_dst[j];
    float4 as_ = *reinterpret_cast<const float4*>(a_src + (size_t)s * 4);
    float4 ad_ = *reinterpret_cast<const float4*>(a_dst + (size_t)d * 4);
    float4 w;
    w.x = __expf(lrelu(as_.x + ad_.x));
    w.y = __expf(lrelu(as_.y + ad_.y));
    w.z = __expf(lrelu(as_.z + ad_.z));
    w.w = __expf(lrelu(as_.w + ad_.w));
    *reinterpret_cast<float4*>(ew + (size_t)j * 4) = w;
}

// ---------------- weighted gather, one wave per node (R8-exact) -------------
// All 64 lanes on ONE edge: lane = channel c, uint2 = heads 0..3 bf16.
// Node index forced wave-uniform via readfirstlane so the per-edge metadata
// (sorted_src, ew) compiles to scalar loads; 8 H-row gathers in flight.
// 8-deep UNGATED groups are the measured optimum (8-deep=67us beats fused=82
// and 16-deep-gated=91): tail over-gather wastes ~3% of bytes but keeps the
// load issue branch-free. Over-read safety: sorted->sortedd and ew->a_src
// are contiguous in the workspace (garbage indices still valid node ids).
// NOTE: macro params named W_/V_ to avoid the preprocessor substituting the
// parameter name inside swizzle members (.w).
#define AGG_ACC(W_, V_)                                                     \
    do {                                                                    \
        a0 += (W_).x * bflo((V_).x); a1 += (W_).y * bfhi((V_).x);           \
        a2 += (W_).z * bflo((V_).y); a3 += (W_).w * bfhi((V_).y);           \
        dp0 += (W_).x; dp1 += (W_).y; dp2 += (W_).z; dp3 += (W_).w;         \
    } while (0)

__global__ __launch_bounds__(256) void agg_kernel(const ushort* __restrict__ H,
                                                  const float* __restrict__ a_src,
                                                  const float* __restrict__ a_dst,
                                                  const int* __restrict__ row_ptr,
                                                  const int* __restrict__ sorted_src,
                                                  const float* __restrict__ ew,
                                                  const float* __restrict__ bias,
                                                  float* __restrict__ out, int N) {
    const int lane = threadIdx.x & 63;
    const int i = __builtin_amdgcn_readfirstlane(blockIdx.x * 4 + (threadIdx.x >> 6));
    if (i >= N) return;
    const float4 asv = *reinterpret_cast<const float4*>(a_src + (size_t)i * 4);
    const float4 adv = *reinterpret_cast<const float4*>(a_dst + (size_t)i * 4);
    const float ws0 = __expf(lrelu(asv.x + adv.x)), ws1 = __expf(lrelu(asv.y + adv.y));
    const float ws2 = __expf(lrelu(asv.z + adv.z)), ws3 = __expf(lrelu(asv.w + adv.w));
    const int start = row_ptr[i], end = row_ptr[i + 1];

    float a0 = 0.f, a1 = 0.f, a2 = 0.f, a3 = 0.f;
    float dp0 = 0.f, dp1 = 0.f, dp2 = 0.f, dp3 = 0.f;
    const ushort* __restrict__ Hl = H + lane * 4;   // this lane's channel slice

    for (int j0 = start; j0 < end; j0 += 8) {
        int s[8];
        #pragma unroll
        for (int k = 0; k < 8; k++) s[k] = sorted_src[j0 + k];        // s_load_dwordx8
        floatx4 w[8];
        #pragma unroll
        for (int k = 0; k < 8; k++)                                   // 2x s_load_dwordx16
            w[k] = *reinterpret_cast<const floatx4*>(ew + (size_t)(j0 + k) * 4);
        uintx2 hv[8];
        #pragma unroll
        for (int k = 0; k < 8; k++)                                   // 8 gathers in flight
            hv[k] = *reinterpret_cast<const uintx2*>(Hl + (size_t)s[k] * 256);
        if (j0 + 8 <= end) {
            #pragma unroll
            for (int k = 0; k < 8; k++) AGG_ACC(w[k], hv[k]);
        } else {
            #pragma unroll
            for (int k = 0; k < 8; k++)
                if (j0 + k < end) AGG_ACC(w[k], hv[k]);               // uniform branch
        }
    }
    // self loop
    {
        uintx2 hv = *reinterpret_cast<const uintx2*>(Hl + (size_t)i * 256);
        a0 += ws0 * bflo(hv.x); a1 += ws1 * bfhi(hv.x);
        a2 += ws2 * bflo(hv.y); a3 += ws3 * bfhi(hv.y);
    }
    const float r0 = 1.f / (dp0 + ws0 + 1e-16f), r1 = 1.f / (dp1 + ws1 + 1e-16f);
    const float r2 = 1.f / (dp2 + ws2 + 1e-16f), r3 = 1.f / (dp3 + ws3 + 1e-16f);
    // out[i*256 + h*64 + c], c = lane; nontemporal: don't evict H from L2
    float* op = out + (size_t)i * 256 + lane;
    float v;
    v = a0 * r0 + bias[lane];        v = (v > 0.f) ? v : expm1f(v);
    __builtin_nontemporal_store(v, op);
    v = a1 * r1 + bias[64 + lane];   v = (v > 0.f) ? v : expm1f(v);
    __builtin_nontemporal_store(v, op + 64);
    v = a2 * r2 + bias[128 + lane];  v = (v > 0.f) ? v : expm1f(v);
    __builtin_nontemporal_store(v, op + 128);
    v = a3 * r3 + bias[192 + lane];  v = (v > 0.f) ? v : expm1f(v);
    __builtin_nontemporal_store(v, op + 192);
}

extern "C" void kernel_launch(void* const* d_in, const int* in_sizes, int n_in,
                              void* d_out, int out_size, void* d_ws, size_t ws_size,
                              hipStream_t stream) {
    const float* x      = (const float*)d_in[0];
    const int*   eidx   = (const int*)d_in[1];
    const float* W1     = (const float*)d_in[2];
    const float* att_s1 = (const float*)d_in[3];
    const float* att_d1 = (const float*)d_in[4];
    const float* b1     = (const float*)d_in[5];
    const float* W2     = (const float*)d_in[6];
    const float* att_s2 = (const float*)d_in[7];
    const float* att_d2 = (const float*)d_in[8];
    const float* b2     = (const float*)d_in[9];
    float* out = (float*)d_out;

    const int N = N_NODES, E = N_EDGES;
    char* ws = (char*)d_ws;
    size_t off = 0;
    auto alloc = [&](size_t bytes) -> void* {
        void* p = ws + off;
        off += (bytes + 255) & ~(size_t)255;
        return p;
    };
    // NOTE: agg_kernel's tail over-read (<=7 slots) relies on (ew -> a_src)
    // and (sorted -> sortedd) being contiguous: E*16 and E*4 are 256-aligned.
    ushort* h       = (ushort*)alloc((size_t)N * 256 * sizeof(ushort));  // 25.6 MB
    float*  ew      = (float*) alloc((size_t)E * 4 * sizeof(float));     // 12.8 MB
    float*  a_src   = (float*) alloc((size_t)N * 4 * sizeof(float));
    float*  a_dst   = (float*) alloc((size_t)N * 4 * sizeof(float));
    int*    cnt     = (int*)   alloc((size_t)N * sizeof(int));
    int*    row_ptr = (int*)   alloc((size_t)(N + 1) * sizeof(int));
    int*    row_tmp = (int*)   alloc((size_t)N * sizeof(int));
    int*    sorted  = (int*)   alloc((size_t)E * sizeof(int));
    int*    sortedd = (int*)   alloc((size_t)E * sizeof(int));
    int*    excl    = (int*)   alloc((size_t)N * sizeof(int));
    int*    partial = (int*)   alloc(256 * sizeof(int));
    ushort* Wt1_hi  = (ushort*)alloc(272 * 256 * sizeof(ushort));   // 256 W^T + 8 att + 8 zero
    ushort* Wt1_lo  = (ushort*)alloc(272 * 256 * sizeof(ushort));
    ushort* Wt2_hi  = (ushort*)alloc(272 * 256 * sizeof(ushort));
    ushort* Wt2_lo  = (ushort*)alloc(272 * 256 * sizeof(ushort));
    float*  x2      = out;   // layer-1 f32 activations live in d_out, overwritten by layer 2
    (void)ws_size; (void)in_sizes; (void)n_in; (void)out_size;

    const int* e_src = eidx;
    const int* e_dst = eidx + E;
    const int nsb = (N + 255) / 256;   // 196 scan blocks
    const int neb = (E + 255) / 256;

    prep_w<<<512, 320, 0, stream>>>(W1, W2, att_s1, att_d1, att_s2, att_d2,
                                    Wt1_hi, Wt1_lo, Wt2_hi, Wt2_lo);
    hipMemsetAsync(cnt, 0, N * sizeof(int), stream);
    deg_kernel<<<neb, 256, 0, stream>>>(e_dst, cnt, E);
    scan1_kernel<<<nsb, 256, 0, stream>>>(cnt, excl, partial, N);
    scan2_kernel<<<1, 256, 0, stream>>>(partial, nsb);
    scan3_kernel<<<nsb, 256, 0, stream>>>(excl, partial, row_ptr, row_tmp, N);
    scatter_kernel<<<neb, 256, 0, stream>>>(e_src, e_dst, row_tmp, sorted, sortedd, E);

    dim3 ggrid((N + 127) / 128, 2);  // 391 x 2 (128 rows per block)
    int nblk = (N + 3) / 4;          // 12500
    // layer 1
    gemm_att_kernel<<<ggrid, 256, 0, stream>>>(x, Wt1_hi, Wt1_lo, att_s1, att_d1,
                                               h, a_src, a_dst, N);
    ew_kernel<<<neb, 256, 0, stream>>>(a_src, a_dst, sorted, sortedd, ew, E);
    agg_kernel<<<nblk, 256, 0, stream>>>(h, a_src, a_dst, row_ptr, sorted, ew, b1, x2, N);
    // layer 2
    gemm_att_kernel<<<ggrid, 256, 0, stream>>>(x2, Wt2_hi, Wt2_lo, att_s2, att_d2,
                                               h, a_src, a_dst, N);
    ew_kernel<<<neb, 256, 0, stream>>>(a_src, a_dst, sorted, sortedd, ew, E);
    agg_kernel<<<nblk, 256, 0, stream>>>(h, a_src, a_dst, row_ptr, sorted, ew, b2, out, N);
}